// Round 2
// baseline (1366.045 us; speedup 1.0000x reference)
//
#include <hip/hip_runtime.h>
#include <float.h>

#define BT    16384      // B*T tokens
#define DM    256        // embedding dim
#define KC    8192       // codebook size
#define TM    64         // tokens per block
#define TK    64         // codes per k-tile
#define NSPLIT 2
#define KPS   (KC / NSPLIT)       // codes per split
#define QOFF  (BT * DM)           // 4194304: start of indices in d_out
#define LOFF  (QOFF + BT)         // loss slot
#define LDSW  68                  // padded row stride (floats)
#define MARGIN 5e-5f              // dot-space candidate margin (need ~1.8e-5)

// ---------------- k_main: fast fmaf GEMM + per-token top-4 dot ----------------
// grid 512: bid&1 = K-split, bid>>1 = token tile. 256 thr = 16ty x 16tx,
// thread tile 4 tokens x 4 codes. Each thread writes its top-4 (dot,k) pairs
// into the token's own output row: slot m = split*16+tx -> float4s 2m (vals),
// 2m+1 (ks). 32 slots * 8 floats = full 256-float row used as scratch.
__global__ __launch_bounds__(256, 2) void k_main(const float* __restrict__ x,
                                                 const float* __restrict__ cb,
                                                 float* __restrict__ out) {
    __shared__ float xs[TM * LDSW];
    __shared__ float cs[TK * LDSW];

    const int tid = threadIdx.x;
    const int ty = tid >> 4, tx = tid & 15;
    const int split = blockIdx.x & 1;
    const int tb    = blockIdx.x >> 1;
    const int t0    = tb * TM;
    const int kb0   = split * KPS;
    const int txc   = tx & 7;

    const int srow = tid >> 4;
    const int sc4  = tid & 15;

    const float4* x4  = (const float4*)x;
    const float4* cb4 = (const float4*)cb;

    float mv[4][4];
    int   mi[4][4];
    #pragma unroll
    for (int i = 0; i < 4; i++)
        #pragma unroll
        for (int j = 0; j < 4; j++) { mv[i][j] = -FLT_MAX; mi[i][j] = 0; }

    for (int k0 = 0; k0 < KPS; k0 += TK) {
        float dot[4][4];
        #pragma unroll
        for (int i = 0; i < 4; i++)
            #pragma unroll
            for (int j = 0; j < 4; j++) dot[i][j] = 0.f;

        for (int d0 = 0; d0 < DM; d0 += 64) {
            __syncthreads();
            const int d04 = d0 >> 2;
            #pragma unroll
            for (int r = 0; r < 4; r++) {
                int row = srow + 16 * r;
                float4 xv = x4[(size_t)(t0 + row) * 64 + d04 + sc4];
                *(float4*)&xs[row * LDSW + sc4 * 4] = xv;
                int gc = sc4 ^ ((row >> 2) & 7);   // pre-swizzled source col
                float4 cv = cb4[(size_t)(kb0 + k0 + row) * 64 + d04 + gc];
                *(float4*)&cs[row * LDSW + sc4 * 4] = cv;
            }
            __syncthreads();

            #pragma unroll
            for (int u = 0; u < 16; u++) {
                float4 xa[4];
                #pragma unroll
                for (int i = 0; i < 4; i++)
                    xa[i] = *(const float4*)&xs[(ty * 4 + i) * LDSW + u * 4];
                const int w = u ^ txc;
                float4 cv[4];
                #pragma unroll
                for (int j = 0; j < 4; j++)
                    cv[j] = *(const float4*)&cs[(tx * 4 + j) * LDSW + w * 4];
                #pragma unroll
                for (int i = 0; i < 4; i++)
                    #pragma unroll
                    for (int j = 0; j < 4; j++) {
                        dot[i][j] = fmaf(xa[i].x, cv[j].x, dot[i][j]);
                        dot[i][j] = fmaf(xa[i].y, cv[j].y, dot[i][j]);
                        dot[i][j] = fmaf(xa[i].z, cv[j].z, dot[i][j]);
                        dot[i][j] = fmaf(xa[i].w, cv[j].w, dot[i][j]);
                    }
            }
        }

        // top-4 insert (descending dot; strict > keeps earliest k on ties)
        const int kk0 = kb0 + k0 + tx * 4;
        #pragma unroll
        for (int i = 0; i < 4; i++)
            #pragma unroll
            for (int j = 0; j < 4; j++) {
                float d = dot[i][j];
                int   kk = kk0 + j;
                if (d > mv[i][3]) {
                    if (d > mv[i][1]) {
                        if (d > mv[i][0]) {
                            mv[i][3]=mv[i][2]; mi[i][3]=mi[i][2];
                            mv[i][2]=mv[i][1]; mi[i][2]=mi[i][1];
                            mv[i][1]=mv[i][0]; mi[i][1]=mi[i][0];
                            mv[i][0]=d;        mi[i][0]=kk;
                        } else {
                            mv[i][3]=mv[i][2]; mi[i][3]=mi[i][2];
                            mv[i][2]=mv[i][1]; mi[i][2]=mi[i][1];
                            mv[i][1]=d;        mi[i][1]=kk;
                        }
                    } else {
                        if (d > mv[i][2]) {
                            mv[i][3]=mv[i][2]; mi[i][3]=mi[i][2];
                            mv[i][2]=d;        mi[i][2]=kk;
                        } else {
                            mv[i][3]=d;        mi[i][3]=kk;
                        }
                    }
                }
            }
    }

    #pragma unroll
    for (int i = 0; i < 4; i++) {
        int t = t0 + ty * 4 + i;
        float4 v4 = { mv[i][0], mv[i][1], mv[i][2], mv[i][3] };
        float4 k4 = { (float)mi[i][0], (float)mi[i][1], (float)mi[i][2], (float)mi[i][3] };
        float4* dst = (float4*)(out + (size_t)t * DM + (split * 16 + tx) * 8);
        dst[0] = v4;
        dst[1] = k4;
    }
}

// ---------------- k_gather: exact np-f32 re-check, gather, loss partials ----
// One wave per token. Candidate = any dot within MARGIN of global max.
// Exact score emulates numpy einsum f32 SSE: 4 serial accumulators over
// d (mod 4), combined fl(fl(s0+s1)+fl(s2+s3)); s = x2 - 2*xc; first-k ties.
__global__ __launch_bounds__(256) void k_gather(const float* __restrict__ x,
                                                const float* __restrict__ cb,
                                                float* __restrict__ out,
                                                float* __restrict__ ws) {
    __shared__ float4 xls[4][64];
    __shared__ int candk[4][20];
    __shared__ float bsum[4];

    const int w = threadIdx.x >> 6;
    const int L = threadIdx.x & 63;
    const int t = blockIdx.x * 4 + w;

    const float4 xv = ((const float4*)x)[(size_t)t * 64 + L];
    xls[w][L] = xv;
    const float4 f = ((const float4*)(out + (size_t)t * DM))[L];
    const bool even = ((L & 1) == 0);

    // x2: any f32 value within ~1e-4 of numpy's works (uniform grid shift)
    double dl = (double)xv.x * xv.x + (double)xv.y * xv.y
              + (double)xv.z * xv.z + (double)xv.w * xv.w;
    #pragma unroll
    for (int off = 32; off; off >>= 1) dl += __shfl_xor(dl, off);
    const float x2 = (float)dl;

    // global max dot
    float lm = even ? fmaxf(fmaxf(f.x, f.y), fmaxf(f.z, f.w)) : -FLT_MAX;
    #pragma unroll
    for (int off = 32; off; off >>= 1) lm = fmaxf(lm, __shfl_xor(lm, off));
    const float thr = lm - MARGIN;

    // collect candidate k's (uniform control flow via ballot)
    int ncand = 0;
    #pragma unroll
    for (int j = 0; j < 4; j++) {
        float vj = (j == 0) ? f.x : (j == 1) ? f.y : (j == 2) ? f.z : f.w;
        bool flag = even && (vj >= thr);
        unsigned long long bal = __ballot(flag);
        while (bal) {
            int src = __ffsll((unsigned long long)bal) - 1;
            bal &= bal - 1;
            float kv = __shfl(vj, src + 1);   // odd neighbor holds k (same comp j)
            if (L == 0 && ncand < 20) candk[w][ncand] = (int)kv;
            ncand++;
        }
    }
    if (ncand > 16) ncand = 16;

    int best;
    if (ncand == 1) {
        best = candk[w][0];
    } else {
        const int g = L >> 2, l4 = L & 3;
        float sex = FLT_MAX;
        int   kk  = 0x7fffffff;
        if (g < ncand) {
            kk = candk[w][g];
            const float* xr = (const float*)&xls[w][0];
            const float* cr = cb + (size_t)kk * DM;
            float acc = 0.f;
            {
#pragma clang fp contract(off)
                #pragma unroll 8
                for (int m = 0; m < 64; m++) {
                    float p = xr[4 * m + l4] * cr[4 * m + l4];
                    acc = acc + p;
                }
            }
            float t1 = acc + __shfl_xor(acc, 1);   // fl(s0+s1) / fl(s2+s3)
            float xc = t1 + __shfl_xor(t1, 2);     // fl((s0+s1)+(s2+s3))
            sex = x2 - 2.0f * xc;                  // == fl(x2 - fl(2*xc))
        }
        #pragma unroll
        for (int off = 32; off; off >>= 1) {
            float os = __shfl_xor(sex, off);
            int   ok = __shfl_xor(kk, off);
            if (os < sex || (os == sex && ok < kk)) { sex = os; kk = ok; }
        }
        best = kk;
    }

    // gather + STE-forward write + loss partial
    const float4 cv = ((const float4*)cb)[(size_t)best * 64 + L];
    float4 e, q;
    e.x = cv.x - xv.x; q.x = xv.x + e.x;
    e.y = cv.y - xv.y; q.y = xv.y + e.y;
    e.z = cv.z - xv.z; q.z = xv.z + e.z;
    e.w = cv.w - xv.w; q.w = xv.w + e.w;
    ((float4*)out)[(size_t)t * 64 + L] = q;
    if (L == 0) out[QOFF + t] = (float)best;

    float ls = e.x * e.x + e.y * e.y + e.z * e.z + e.w * e.w;
    #pragma unroll
    for (int off = 32; off; off >>= 1) ls += __shfl_xor(ls, off);
    if (L == 0) bsum[w] = ls;
    __syncthreads();
    if (threadIdx.x == 0)
        ws[blockIdx.x] = bsum[0] + bsum[1] + bsum[2] + bsum[3];
}

// ---------------- k_loss: finalize ----------------
__global__ __launch_bounds__(256) void k_loss(const float* __restrict__ ws,
                                              float* __restrict__ out) {
    __shared__ double sd[256];
    double s = 0.0;
    for (int i = threadIdx.x; i < BT / 4; i += 256) s += (double)ws[i];
    sd[threadIdx.x] = s;
    __syncthreads();
    for (int st = 128; st; st >>= 1) {
        if (threadIdx.x < st) sd[threadIdx.x] += sd[threadIdx.x + st];
        __syncthreads();
    }
    if (threadIdx.x == 0)
        out[LOFF] = (float)(2.0 * sd[0] / (double)QOFF);
}

extern "C" void kernel_launch(void* const* d_in, const int* in_sizes, int n_in,
                              void* d_out, int out_size, void* d_ws, size_t ws_size,
                              hipStream_t stream) {
    const float* x  = (const float*)d_in[0];
    const float* cb = (const float*)d_in[1];
    float* out = (float*)d_out;
    float* ws  = (float*)d_ws;   // [0,4096): per-block loss partials

    k_main  <<<(BT / TM) * NSPLIT, 256, 0, stream>>>(x, cb, out);
    k_gather<<<BT / 4,             256, 0, stream>>>(x, cb, out, ws);
    k_loss  <<<1,                  256, 0, stream>>>(ws, out);
}

// Round 3
// 257.709 us; speedup vs baseline: 5.3007x; 5.3007x over previous
//
#include <hip/hip_runtime.h>
#include <float.h>

typedef __attribute__((ext_vector_type(8))) short short8;
typedef __attribute__((ext_vector_type(4))) float f32x4;

#define BT    16384      // B*T tokens
#define DM    256        // embedding dim
#define KC    8192       // codebook size
#define QOFF  (BT * DM)  // start of indices in d_out
#define LOFF  (QOFF + BT)
#define MARGIN 5e-5f

// ws layout (ushort elems for split arrays)
#define E_XH 0
#define E_XL (BT * DM)
#define E_CH (2 * BT * DM)
#define E_CL (2 * BT * DM + KC * DM)
#define WS_LP_BYTES ((size_t)(2 * BT * DM + 2 * KC * DM) * 2)   // 25165824
#define WS_NEED (WS_LP_BYTES + 4096 * 4)

// ======================= MFMA path =======================

__device__ inline ushort bf16rne(float f) {
    unsigned u = __float_as_uint(f);
    return (ushort)((u + 0x7FFFu + ((u >> 16) & 1u)) >> 16);
}
__device__ inline float bf2f(ushort h) { return __uint_as_float((unsigned)h << 16); }

// k_cvt: one-time hi/lo bf16 split of x and codebook into ws
__global__ __launch_bounds__(256) void k_cvt(const float* __restrict__ x,
                                             const float* __restrict__ cb,
                                             ushort* __restrict__ ws) {
    const int XN = BT * DM / 4;   // 1048576 float4s
    const int CN = KC * DM / 4;   // 524288
    int idx = blockIdx.x * 256 + threadIdx.x;
    const float4* src;
    ushort* dh; ushort* dl; int o;
    if (idx < XN) { src = (const float4*)x;  dh = ws + E_XH; dl = ws + E_XL; o = idx; }
    else {
        o = idx - XN;
        if (o >= CN) return;
        src = (const float4*)cb; dh = ws + E_CH; dl = ws + E_CL;
    }
    float4 v = src[o];
    ushort4 h, l;
    h.x = bf16rne(v.x); l.x = bf16rne(v.x - bf2f(h.x));
    h.y = bf16rne(v.y); l.y = bf16rne(v.y - bf2f(h.y));
    h.z = bf16rne(v.z); l.z = bf16rne(v.z - bf2f(h.z));
    h.w = bf16rne(v.w); l.w = bf16rne(v.w - bf2f(h.w));
    ((ushort4*)dh)[o] = h;
    ((ushort4*)dl)[o] = l;
}

// k_main_mfma: 3-product bf16-split GEMM + per-(lane,token) top-2.
// grid 512 = 4 splits x 128 token-tiles. Block: 128 codes x 128 tokens,
// 4 waves (wm,wn in 2x2), wave tile 64x64 via 4x4 16x16x32 fragments.
// LDS: Ah,Al,Bh,Bl [128 rows][64 d] bf16, XOR-granule swizzle (^row&7).
__global__ __launch_bounds__(256, 2) void k_main_mfma(const ushort* __restrict__ ws,
                                                      float* __restrict__ out) {
    __shared__ ushort lds[4 * 8192];   // 64 KB

    const int tid = threadIdx.x;
    const int w   = tid >> 6;          // wave 0..3
    const int L   = tid & 63;
    const int wm  = w >> 1, wn = w & 1;
    const int split = blockIdx.x >> 7;
    const int tt    = blockIdx.x & 127;
    const int t0    = tt * 128;
    const int lq = L >> 4, lr = L & 15;

    // staging: wave w owns array w (0:Ch 1:Cl 2:Xh 3:Xl)
    const ushort* sb = (w == 0) ? ws + E_CH : (w == 1) ? ws + E_CL
                     : (w == 2) ? ws + E_XH : ws + E_XL;
    const uint4* sb4 = (const uint4*)sb;             // 16B granules (8 elems)
    ushort* larr = lds + w * 8192;
    const int lrow = L >> 3, lg = L & 7;             // stage row-in-8 / granule
    const int lswz = (lg ^ lrow) * 8;                // swizzled LDS granule off

    // frag-read lane constants
    const int rswz = lr & 7;                         // row&7 for frag rows

    float v1[4], v2[4]; int k1[4], k2[4];
    #pragma unroll
    for (int j = 0; j < 4; ++j) { v1[j] = -FLT_MAX; v2[j] = -FLT_MAX; k1[j] = 0; k2[j] = 0; }

    for (int ct = 0; ct < 16; ++ct) {
        const int cb0 = split * 2048 + ct * 128;
        const int srowbase = (w < 2) ? cb0 : t0;

        f32x4 acc[4][4];
        #pragma unroll
        for (int i = 0; i < 4; ++i)
            #pragma unroll
            for (int j = 0; j < 4; ++j) acc[i][j] = (f32x4){0.f, 0.f, 0.f, 0.f};

        for (int dc = 0; dc < 4; ++dc) {        // d0 = dc*64
            const int d08 = dc * 8;             // d0 in granules
            __syncthreads();
            #pragma unroll 4
            for (int q = 0; q < 16; ++q) {      // 8 rows per q
                uint4 tv = sb4[(size_t)(srowbase + q * 8 + lrow) * 32 + d08 + lg];
                *(uint4*)(larr + q * 512 + lrow * 64 + lswz) = tv;
            }
            __syncthreads();

            #pragma unroll
            for (int ks = 0; ks < 2; ++ks) {    // two K=32 steps in the 64-chunk
                const int gsw = ((ks * 4 + lq) ^ rswz) * 8;
                short8 ah[4], al[4], bh[4], bl[4];
                #pragma unroll
                for (int i = 0; i < 4; ++i) {
                    int ro = (wm * 64 + i * 16 + lr) * 64 + gsw;
                    ah[i] = *(const short8*)(lds + ro);
                    al[i] = *(const short8*)(lds + 8192 + ro);
                }
                #pragma unroll
                for (int j = 0; j < 4; ++j) {
                    int ro = (wn * 64 + j * 16 + lr) * 64 + gsw;
                    bh[j] = *(const short8*)(lds + 16384 + ro);
                    bl[j] = *(const short8*)(lds + 24576 + ro);
                }
                #pragma unroll
                for (int i = 0; i < 4; ++i)
                    #pragma unroll
                    for (int j = 0; j < 4; ++j) {
                        acc[i][j] = __builtin_amdgcn_mfma_f32_16x16x32_bf16(ah[i], bh[j], acc[i][j], 0, 0, 0);
                        acc[i][j] = __builtin_amdgcn_mfma_f32_16x16x32_bf16(ah[i], bl[j], acc[i][j], 0, 0, 0);
                        acc[i][j] = __builtin_amdgcn_mfma_f32_16x16x32_bf16(al[i], bh[j], acc[i][j], 0, 0, 0);
                    }
            }
        }

        // top-2 insert per (lane, token j), pruned by max-of-4
        #pragma unroll
        for (int j = 0; j < 4; ++j)
            #pragma unroll
            for (int i = 0; i < 4; ++i) {
                f32x4 a = acc[i][j];
                float m = fmaxf(fmaxf(a[0], a[1]), fmaxf(a[2], a[3]));
                if (m > v2[j]) {
                    const int cbase = cb0 + wm * 64 + i * 16 + lq * 4;
                    #pragma unroll
                    for (int r = 0; r < 4; ++r) {
                        float d = a[r]; int kk = cbase + r;
                        if (d > v2[j]) {
                            if (d > v1[j]) { v2[j] = v1[j]; k2[j] = k1[j]; v1[j] = d; k1[j] = kk; }
                            else           { v2[j] = d; k2[j] = kk; }
                        }
                    }
                }
            }
    }

    // epilogue: 32 candidate slots per token, slot = split*8 + wm*4 + lq
    #pragma unroll
    for (int j = 0; j < 4; ++j) {
        int token = t0 + wn * 64 + j * 16 + lr;
        float4 o = { v1[j], (float)k1[j], v2[j], (float)k2[j] };
        *(float4*)(out + (size_t)token * DM + (split * 8 + wm * 4 + lq) * 4) = o;
    }
}

// k_gather_mfma: candidates from 32 slots, exact np-f32 re-check, gather, loss
__global__ __launch_bounds__(256) void k_gather_mfma(const float* __restrict__ x,
                                                     const float* __restrict__ cb,
                                                     float* __restrict__ out,
                                                     float* __restrict__ lp) {
    __shared__ float4 xls[4][64];
    __shared__ int candk[4][16];
    __shared__ float bsum[4];

    const int w = threadIdx.x >> 6;
    const int L = threadIdx.x & 63;
    const int t = blockIdx.x * 4 + w;

    const float4 xv = ((const float4*)x)[(size_t)t * 64 + L];
    xls[w][L] = xv;
    float4 f;
    if (L < 32) f = ((const float4*)(out + (size_t)t * DM))[L];
    else { f.x = -FLT_MAX; f.y = 0.f; f.z = -FLT_MAX; f.w = 0.f; }
    __syncthreads();   // drain slot reads before row overwrite

    // x2 (any f32 within ~1e-4 of numpy's: uniform grid shift)
    double dl = (double)xv.x * xv.x + (double)xv.y * xv.y
              + (double)xv.z * xv.z + (double)xv.w * xv.w;
    #pragma unroll
    for (int off = 32; off; off >>= 1) dl += __shfl_xor(dl, off);
    const float x2 = (float)dl;

    float lm = fmaxf(f.x, f.z);
    #pragma unroll
    for (int off = 32; off; off >>= 1) lm = fmaxf(lm, __shfl_xor(lm, off));
    const float thr = lm - MARGIN;

    int ncand = 0;
    #pragma unroll
    for (int p = 0; p < 2; ++p) {
        float vv = p ? f.z : f.x;
        float kf = p ? f.w : f.y;
        unsigned long long bal = __ballot(vv >= thr);
        while (bal) {
            int src = __ffsll(bal) - 1;
            bal &= bal - 1;
            float kv = __shfl(kf, src);
            if (L == 0 && ncand < 16) candk[w][ncand] = (int)kv;
            ncand++;
        }
    }
    if (ncand > 16) ncand = 16;

    int best;
    if (ncand == 1) {
        best = candk[w][0];
    } else {
        const int g = L >> 2, l4 = L & 3;
        float sex = FLT_MAX;
        int   kk  = 0x7fffffff;
        if (g < ncand) {
            kk = candk[w][g];
            const float* xr = (const float*)&xls[w][0];
            const float* cr = cb + (size_t)kk * DM;
            float acc = 0.f;
            {
#pragma clang fp contract(off)
                #pragma unroll 8
                for (int m = 0; m < 64; m++) {
                    float p2 = xr[4 * m + l4] * cr[4 * m + l4];
                    acc = acc + p2;
                }
            }
            float t1 = acc + __shfl_xor(acc, 1);   // fl(s0+s1)/fl(s2+s3)
            float xc = t1 + __shfl_xor(t1, 2);     // np 4-acc SSE combine
            sex = x2 - 2.0f * xc;
        }
        #pragma unroll
        for (int off = 32; off; off >>= 1) {
            float os = __shfl_xor(sex, off);
            int   ok = __shfl_xor(kk, off);
            if (os < sex || (os == sex && ok < kk)) { sex = os; kk = ok; }
        }
        best = kk;
    }

    const float4 cv = ((const float4*)cb)[(size_t)best * 64 + L];
    float4 e, q;
    e.x = cv.x - xv.x; q.x = xv.x + e.x;
    e.y = cv.y - xv.y; q.y = xv.y + e.y;
    e.z = cv.z - xv.z; q.z = xv.z + e.z;
    e.w = cv.w - xv.w; q.w = xv.w + e.w;
    ((float4*)out)[(size_t)t * 64 + L] = q;
    if (L == 0) out[QOFF + t] = (float)best;

    float ls = e.x * e.x + e.y * e.y + e.z * e.z + e.w * e.w;
    #pragma unroll
    for (int off = 32; off; off >>= 1) ls += __shfl_xor(ls, off);
    if (L == 0) bsum[w] = ls;
    __syncthreads();
    if (threadIdx.x == 0)
        lp[blockIdx.x] = bsum[0] + bsum[1] + bsum[2] + bsum[3];
}

// ======================= fallback f32 path (round-2, verified) =======================

#define TM    64
#define TK    64
#define NSPLIT 2
#define KPS   (KC / NSPLIT)
#define LDSW  68

__global__ __launch_bounds__(256, 2) void k_main_f32(const float* __restrict__ x,
                                                     const float* __restrict__ cb,
                                                     float* __restrict__ out) {
    __shared__ float xs[TM * LDSW];
    __shared__ float cs[TK * LDSW];

    const int tid = threadIdx.x;
    const int ty = tid >> 4, tx = tid & 15;
    const int split = blockIdx.x & 1;
    const int tb    = blockIdx.x >> 1;
    const int t0    = tb * TM;
    const int kb0   = split * KPS;
    const int txc   = tx & 7;
    const int srow = tid >> 4;
    const int sc4  = tid & 15;
    const float4* x4  = (const float4*)x;
    const float4* cb4 = (const float4*)cb;

    float mv[4][4];
    int   mi[4][4];
    #pragma unroll
    for (int i = 0; i < 4; i++)
        #pragma unroll
        for (int j = 0; j < 4; j++) { mv[i][j] = -FLT_MAX; mi[i][j] = 0; }

    for (int k0 = 0; k0 < KPS; k0 += TK) {
        float dot[4][4];
        #pragma unroll
        for (int i = 0; i < 4; i++)
            #pragma unroll
            for (int j = 0; j < 4; j++) dot[i][j] = 0.f;

        for (int d0 = 0; d0 < DM; d0 += 64) {
            __syncthreads();
            const int d04 = d0 >> 2;
            #pragma unroll
            for (int r = 0; r < 4; r++) {
                int row = srow + 16 * r;
                float4 xv = x4[(size_t)(t0 + row) * 64 + d04 + sc4];
                *(float4*)&xs[row * LDSW + sc4 * 4] = xv;
                int gc = sc4 ^ ((row >> 2) & 7);
                float4 cv = cb4[(size_t)(kb0 + k0 + row) * 64 + d04 + gc];
                *(float4*)&cs[row * LDSW + sc4 * 4] = cv;
            }
            __syncthreads();

            #pragma unroll
            for (int u = 0; u < 16; u++) {
                float4 xa[4];
                #pragma unroll
                for (int i = 0; i < 4; i++)
                    xa[i] = *(const float4*)&xs[(ty * 4 + i) * LDSW + u * 4];
                const int ww = u ^ txc;
                float4 cv[4];
                #pragma unroll
                for (int j = 0; j < 4; j++)
                    cv[j] = *(const float4*)&cs[(tx * 4 + j) * LDSW + ww * 4];
                #pragma unroll
                for (int i = 0; i < 4; i++)
                    #pragma unroll
                    for (int j = 0; j < 4; j++) {
                        dot[i][j] = fmaf(xa[i].x, cv[j].x, dot[i][j]);
                        dot[i][j] = fmaf(xa[i].y, cv[j].y, dot[i][j]);
                        dot[i][j] = fmaf(xa[i].z, cv[j].z, dot[i][j]);
                        dot[i][j] = fmaf(xa[i].w, cv[j].w, dot[i][j]);
                    }
            }
        }

        const int kk0 = kb0 + k0 + tx * 4;
        #pragma unroll
        for (int i = 0; i < 4; i++)
            #pragma unroll
            for (int j = 0; j < 4; j++) {
                float d = dot[i][j];
                int   kk = kk0 + j;
                if (d > mv[i][3]) {
                    if (d > mv[i][1]) {
                        if (d > mv[i][0]) {
                            mv[i][3]=mv[i][2]; mi[i][3]=mi[i][2];
                            mv[i][2]=mv[i][1]; mi[i][2]=mi[i][1];
                            mv[i][1]=mv[i][0]; mi[i][1]=mi[i][0];
                            mv[i][0]=d;        mi[i][0]=kk;
                        } else {
                            mv[i][3]=mv[i][2]; mi[i][3]=mi[i][2];
                            mv[i][2]=mv[i][1]; mi[i][2]=mi[i][1];
                            mv[i][1]=d;        mi[i][1]=kk;
                        }
                    } else {
                        if (d > mv[i][2]) {
                            mv[i][3]=mv[i][2]; mi[i][3]=mi[i][2];
                            mv[i][2]=d;        mi[i][2]=kk;
                        } else {
                            mv[i][3]=d;        mi[i][3]=kk;
                        }
                    }
                }
            }
    }

    #pragma unroll
    for (int i = 0; i < 4; i++) {
        int t = t0 + ty * 4 + i;
        float4 v4 = { mv[i][0], mv[i][1], mv[i][2], mv[i][3] };
        float4 k4 = { (float)mi[i][0], (float)mi[i][1], (float)mi[i][2], (float)mi[i][3] };
        float4* dst = (float4*)(out + (size_t)t * DM + (split * 16 + tx) * 8);
        dst[0] = v4;
        dst[1] = k4;
    }
}

__global__ __launch_bounds__(256) void k_gather_f32(const float* __restrict__ x,
                                                    const float* __restrict__ cb,
                                                    float* __restrict__ out,
                                                    float* __restrict__ lp) {
    __shared__ float4 xls[4][64];
    __shared__ int candk[4][20];
    __shared__ float bsum[4];

    const int w = threadIdx.x >> 6;
    const int L = threadIdx.x & 63;
    const int t = blockIdx.x * 4 + w;

    const float4 xv = ((const float4*)x)[(size_t)t * 64 + L];
    xls[w][L] = xv;
    const float4 f = ((const float4*)(out + (size_t)t * DM))[L];
    const bool even = ((L & 1) == 0);

    double dl = (double)xv.x * xv.x + (double)xv.y * xv.y
              + (double)xv.z * xv.z + (double)xv.w * xv.w;
    #pragma unroll
    for (int off = 32; off; off >>= 1) dl += __shfl_xor(dl, off);
    const float x2 = (float)dl;

    float lm = even ? fmaxf(fmaxf(f.x, f.y), fmaxf(f.z, f.w)) : -FLT_MAX;
    #pragma unroll
    for (int off = 32; off; off >>= 1) lm = fmaxf(lm, __shfl_xor(lm, off));
    const float thr = lm - MARGIN;

    int ncand = 0;
    #pragma unroll
    for (int j = 0; j < 4; j++) {
        float vj = (j == 0) ? f.x : (j == 1) ? f.y : (j == 2) ? f.z : f.w;
        bool flag = even && (vj >= thr);
        unsigned long long bal = __ballot(flag);
        while (bal) {
            int src = __ffsll(bal) - 1;
            bal &= bal - 1;
            float kv = __shfl(vj, src + 1);
            if (L == 0 && ncand < 20) candk[w][ncand] = (int)kv;
            ncand++;
        }
    }
    if (ncand > 16) ncand = 16;

    int best;
    if (ncand == 1) {
        best = candk[w][0];
    } else {
        const int g = L >> 2, l4 = L & 3;
        float sex = FLT_MAX;
        int   kk  = 0x7fffffff;
        if (g < ncand) {
            kk = candk[w][g];
            const float* xr = (const float*)&xls[w][0];
            const float* cr = cb + (size_t)kk * DM;
            float acc = 0.f;
            {
#pragma clang fp contract(off)
                #pragma unroll 8
                for (int m = 0; m < 64; m++) {
                    float p = xr[4 * m + l4] * cr[4 * m + l4];
                    acc = acc + p;
                }
            }
            float t1 = acc + __shfl_xor(acc, 1);
            float xc = t1 + __shfl_xor(t1, 2);
            sex = x2 - 2.0f * xc;
        }
        #pragma unroll
        for (int off = 32; off; off >>= 1) {
            float os = __shfl_xor(sex, off);
            int   ok = __shfl_xor(kk, off);
            if (os < sex || (os == sex && ok < kk)) { sex = os; kk = ok; }
        }
        best = kk;
    }

    const float4 cv = ((const float4*)cb)[(size_t)best * 64 + L];
    float4 e, q;
    e.x = cv.x - xv.x; q.x = xv.x + e.x;
    e.y = cv.y - xv.y; q.y = xv.y + e.y;
    e.z = cv.z - xv.z; q.z = xv.z + e.z;
    e.w = cv.w - xv.w; q.w = xv.w + e.w;
    ((float4*)out)[(size_t)t * 64 + L] = q;
    if (L == 0) out[QOFF + t] = (float)best;

    float ls = e.x * e.x + e.y * e.y + e.z * e.z + e.w * e.w;
    #pragma unroll
    for (int off = 32; off; off >>= 1) ls += __shfl_xor(ls, off);
    if (L == 0) bsum[w] = ls;
    __syncthreads();
    if (threadIdx.x == 0)
        lp[blockIdx.x] = bsum[0] + bsum[1] + bsum[2] + bsum[3];
}

// ---------------- shared loss finalize ----------------
__global__ __launch_bounds__(256) void k_loss(const float* __restrict__ lp,
                                              float* __restrict__ out) {
    __shared__ double sd[256];
    double s = 0.0;
    for (int i = threadIdx.x; i < BT / 4; i += 256) s += (double)lp[i];
    sd[threadIdx.x] = s;
    __syncthreads();
    for (int st = 128; st; st >>= 1) {
        if (threadIdx.x < st) sd[threadIdx.x] += sd[threadIdx.x + st];
        __syncthreads();
    }
    if (threadIdx.x == 0)
        out[LOFF] = (float)(2.0 * sd[0] / (double)QOFF);
}

extern "C" void kernel_launch(void* const* d_in, const int* in_sizes, int n_in,
                              void* d_out, int out_size, void* d_ws, size_t ws_size,
                              hipStream_t stream) {
    const float* x  = (const float*)d_in[0];
    const float* cb = (const float*)d_in[1];
    float* out = (float*)d_out;

    if (ws_size >= (size_t)WS_NEED) {
        ushort* wsu = (ushort*)d_ws;
        float*  lp  = (float*)((char*)d_ws + WS_LP_BYTES);
        k_cvt        <<<6144, 256, 0, stream>>>(x, cb, wsu);
        k_main_mfma  <<<512,  256, 0, stream>>>(wsu, out);
        k_gather_mfma<<<BT / 4, 256, 0, stream>>>(x, cb, out, lp);
        k_loss       <<<1,    256, 0, stream>>>(lp, out);
    } else {
        float* lp = (float*)d_ws;
        k_main_f32  <<<(BT / TM) * NSPLIT, 256, 0, stream>>>(x, cb, out);
        k_gather_f32<<<BT / 4,             256, 0, stream>>>(x, cb, out, lp);
        k_loss      <<<1,                  256, 0, stream>>>(lp, out);
    }
}

// Round 4
// 237.006 us; speedup vs baseline: 5.7637x; 1.0874x over previous
//
#include <hip/hip_runtime.h>
#include <float.h>

typedef __attribute__((ext_vector_type(8))) short short8;
typedef __attribute__((ext_vector_type(4))) float f32x4;

#define BT    16384      // B*T tokens
#define DM    256        // embedding dim
#define KC    8192       // codebook size
#define QOFF  (BT * DM)  // start of indices in d_out
#define LOFF  (QOFF + BT)
#define MARGIN 2e-4f

// ws layout (ushort elems): bf16 x and codebook (hi only)
#define E_XH 0
#define E_CH (BT * DM)
#define WS_LP_BYTES ((size_t)(BT * DM + KC * DM) * 2)   // 12582912
#define WS_NEED (WS_LP_BYTES + 4096 * 4)

// ======================= MFMA path =======================

__device__ inline ushort bf16rne(float f) {
    unsigned u = __float_as_uint(f);
    return (ushort)((u + 0x7FFFu + ((u >> 16) & 1u)) >> 16);
}

// k_cvt: one-time bf16 round of x and codebook into ws
__global__ __launch_bounds__(256) void k_cvt(const float* __restrict__ x,
                                             const float* __restrict__ cb,
                                             ushort* __restrict__ ws) {
    const int XN = BT * DM / 4;   // 1048576 float4s
    const int CN = KC * DM / 4;   // 524288
    int idx = blockIdx.x * 256 + threadIdx.x;
    const float4* src;
    ushort* dh; int o;
    if (idx < XN) { src = (const float4*)x; dh = ws + E_XH; o = idx; }
    else {
        o = idx - XN;
        if (o >= CN) return;
        src = (const float4*)cb; dh = ws + E_CH;
    }
    float4 v = src[o];
    ushort4 h;
    h.x = bf16rne(v.x);
    h.y = bf16rne(v.y);
    h.z = bf16rne(v.z);
    h.w = bf16rne(v.w);
    ((ushort4*)dh)[o] = h;
}

// k_main_mfma: single-product bf16 GEMM + per-(lane,token) top-2.
// grid 512 = 64 token-tiles x 8 splits (split = bid&7 -> XCD-resident L2 slice).
// Block: 128 codes x 256 tokens, 4 waves (wm=code 2 x wn=token 2),
// wave tile 64 codes x 128 tokens via 4x8 16x16x32 fragments.
// LDS: A=codes [128][64], B=tokens [256][64] bf16, XOR-granule swizzle.
__global__ __launch_bounds__(256, 2) void k_main_mfma(const ushort* __restrict__ ws,
                                                      float* __restrict__ out) {
    __shared__ ushort lds[128 * 64 + 256 * 64];   // 48 KB: A at 0, B at 8192

    const int tid = threadIdx.x;
    const int w   = tid >> 6;          // wave 0..3
    const int L   = tid & 63;
    const int wm  = w >> 1, wn = w & 1;
    const int split = blockIdx.x & 7;
    const int t0    = (blockIdx.x >> 3) * 256;
    const int lq = L >> 4, lr = L & 15;
    const int rswz = lr & 7;

    const uint4* ch4 = (const uint4*)(ws + E_CH);   // codes, 16B granules
    const uint4* xh4 = (const uint4*)(ws + E_XH);   // tokens

    const int srow = tid >> 3;                      // staging row-in-32 (0..31)
    const int sg   = tid & 7;                       // staging granule
    const int sswz = (sg ^ (srow & 7)) * 8;         // swizzled elem offset

    float v1[8], v2[8]; int k1[8], k2[8];
    #pragma unroll
    for (int j = 0; j < 8; ++j) { v1[j] = -FLT_MAX; v2[j] = -FLT_MAX; k1[j] = 0; k2[j] = 0; }

    for (int ct = 0; ct < 8; ++ct) {
        const int cb0 = split * 1024 + ct * 128;

        f32x4 acc[4][8];
        #pragma unroll
        for (int i = 0; i < 4; ++i)
            #pragma unroll
            for (int j = 0; j < 8; ++j) acc[i][j] = (f32x4){0.f, 0.f, 0.f, 0.f};

        for (int dc = 0; dc < 4; ++dc) {          // 64-d chunks
            const int d08 = dc * 8;               // chunk offset in granules
            __syncthreads();
            #pragma unroll
            for (int q = 0; q < 4; ++q) {         // A: 128 code rows
                int row = q * 32 + srow;
                uint4 tv = ch4[(size_t)(cb0 + row) * 32 + d08 + sg];
                *(uint4*)(lds + row * 64 + sswz) = tv;
            }
            #pragma unroll
            for (int q = 0; q < 8; ++q) {         // B: 256 token rows
                int row = q * 32 + srow;
                uint4 tv = xh4[(size_t)(t0 + row) * 32 + d08 + sg];
                *(uint4*)(lds + 8192 + row * 64 + sswz) = tv;
            }
            __syncthreads();

            #pragma unroll
            for (int ks = 0; ks < 2; ++ks) {      // two K=32 steps
                const int gsw = ((ks * 4 + lq) ^ rswz) * 8;
                short8 ah[4], bh[8];
                #pragma unroll
                for (int i = 0; i < 4; ++i)
                    ah[i] = *(const short8*)(lds + (wm * 64 + i * 16 + lr) * 64 + gsw);
                #pragma unroll
                for (int j = 0; j < 8; ++j)
                    bh[j] = *(const short8*)(lds + 8192 + (wn * 128 + j * 16 + lr) * 64 + gsw);
                #pragma unroll
                for (int i = 0; i < 4; ++i)
                    #pragma unroll
                    for (int j = 0; j < 8; ++j)
                        acc[i][j] = __builtin_amdgcn_mfma_f32_16x16x32_bf16(ah[i], bh[j], acc[i][j], 0, 0, 0);
            }
        }

        // top-2 insert per (lane, token frag j), pruned by max-of-4
        #pragma unroll
        for (int j = 0; j < 8; ++j)
            #pragma unroll
            for (int i = 0; i < 4; ++i) {
                f32x4 a = acc[i][j];
                float m = fmaxf(fmaxf(a[0], a[1]), fmaxf(a[2], a[3]));
                if (m > v2[j]) {
                    const int cbase = cb0 + wm * 64 + i * 16 + lq * 4;
                    #pragma unroll
                    for (int r = 0; r < 4; ++r) {
                        float d = a[r]; int kk = cbase + r;
                        if (d > v2[j]) {
                            if (d > v1[j]) { v2[j] = v1[j]; k2[j] = k1[j]; v1[j] = d; k1[j] = kk; }
                            else           { v2[j] = d; k2[j] = kk; }
                        }
                    }
                }
            }
    }

    // epilogue: 64 candidate slots per token, slot = split*8 + wm*4 + lq
    #pragma unroll
    for (int j = 0; j < 8; ++j) {
        int token = t0 + wn * 128 + j * 16 + lr;
        float4 o = { v1[j], (float)k1[j], v2[j], (float)k2[j] };
        *(float4*)(out + (size_t)token * DM + (split * 8 + wm * 4 + lq) * 4) = o;
    }
}

// k_gather_mfma: candidates from 64 slots, exact np-f32 re-check, gather, loss
__global__ __launch_bounds__(256) void k_gather_mfma(const float* __restrict__ x,
                                                     const float* __restrict__ cb,
                                                     float* __restrict__ out,
                                                     float* __restrict__ lp) {
    __shared__ float4 xls[4][64];
    __shared__ int candk[4][16];
    __shared__ float bsum[4];

    const int w = threadIdx.x >> 6;
    const int L = threadIdx.x & 63;
    const int t = blockIdx.x * 4 + w;

    const float4 xv = ((const float4*)x)[(size_t)t * 64 + L];
    xls[w][L] = xv;
    const float4 f = ((const float4*)(out + (size_t)t * DM))[L];   // slot L
    __syncthreads();   // drain slot reads before row overwrite

    // x2 (any f32 within ~1e-4 of numpy's: uniform grid shift)
    double dl = (double)xv.x * xv.x + (double)xv.y * xv.y
              + (double)xv.z * xv.z + (double)xv.w * xv.w;
    #pragma unroll
    for (int off = 32; off; off >>= 1) dl += __shfl_xor(dl, off);
    const float x2 = (float)dl;

    float lm = fmaxf(f.x, f.z);
    #pragma unroll
    for (int off = 32; off; off >>= 1) lm = fmaxf(lm, __shfl_xor(lm, off));
    const float thr = lm - MARGIN;

    int ncand = 0;
    #pragma unroll
    for (int p = 0; p < 2; ++p) {
        float vv = p ? f.z : f.x;
        float kf = p ? f.w : f.y;
        unsigned long long bal = __ballot(vv >= thr);
        while (bal) {
            int src = __ffsll(bal) - 1;
            bal &= bal - 1;
            float kv = __shfl(kf, src);
            if (L == 0 && ncand < 16) candk[w][ncand] = (int)kv;
            ncand++;
        }
    }
    if (ncand > 16) ncand = 16;

    int best;
    if (ncand == 1) {
        best = candk[w][0];
    } else {
        const int g = L >> 2, l4 = L & 3;
        float sex = FLT_MAX;
        int   kk  = 0x7fffffff;
        if (g < ncand) {
            kk = candk[w][g];
            const float* xr = (const float*)&xls[w][0];
            const float* cr = cb + (size_t)kk * DM;
            float acc = 0.f;
            {
#pragma clang fp contract(off)
                #pragma unroll 8
                for (int m = 0; m < 64; m++) {
                    float p2 = xr[4 * m + l4] * cr[4 * m + l4];
                    acc = acc + p2;
                }
            }
            float t1 = acc + __shfl_xor(acc, 1);   // fl(s0+s1)/fl(s2+s3)
            float xc = t1 + __shfl_xor(t1, 2);     // np 4-acc SSE combine
            sex = x2 - 2.0f * xc;
        }
        #pragma unroll
        for (int off = 32; off; off >>= 1) {
            float os = __shfl_xor(sex, off);
            int   ok = __shfl_xor(kk, off);
            if (os < sex || (os == sex && ok < kk)) { sex = os; kk = ok; }
        }
        best = kk;
    }

    const float4 cv = ((const float4*)cb)[(size_t)best * 64 + L];
    float4 e, q;
    e.x = cv.x - xv.x; q.x = xv.x + e.x;
    e.y = cv.y - xv.y; q.y = xv.y + e.y;
    e.z = cv.z - xv.z; q.z = xv.z + e.z;
    e.w = cv.w - xv.w; q.w = xv.w + e.w;
    ((float4*)out)[(size_t)t * 64 + L] = q;
    if (L == 0) out[QOFF + t] = (float)best;

    float ls = e.x * e.x + e.y * e.y + e.z * e.z + e.w * e.w;
    #pragma unroll
    for (int off = 32; off; off >>= 1) ls += __shfl_xor(ls, off);
    if (L == 0) bsum[w] = ls;
    __syncthreads();
    if (threadIdx.x == 0)
        lp[blockIdx.x] = bsum[0] + bsum[1] + bsum[2] + bsum[3];
}

// ======================= fallback f32 path (round-2, verified) =======================

#define TM    64
#define TK    64
#define NSPLIT 2
#define KPS   (KC / NSPLIT)
#define LDSW  68

__global__ __launch_bounds__(256, 2) void k_main_f32(const float* __restrict__ x,
                                                     const float* __restrict__ cb,
                                                     float* __restrict__ out) {
    __shared__ float xs[TM * LDSW];
    __shared__ float cs[TK * LDSW];

    const int tid = threadIdx.x;
    const int ty = tid >> 4, tx = tid & 15;
    const int split = blockIdx.x & 1;
    const int tb    = blockIdx.x >> 1;
    const int t0    = tb * TM;
    const int kb0   = split * KPS;
    const int txc   = tx & 7;
    const int srow = tid >> 4;
    const int sc4  = tid & 15;
    const float4* x4  = (const float4*)x;
    const float4* cb4 = (const float4*)cb;

    float mv[4][4];
    int   mi[4][4];
    #pragma unroll
    for (int i = 0; i < 4; i++)
        #pragma unroll
        for (int j = 0; j < 4; j++) { mv[i][j] = -FLT_MAX; mi[i][j] = 0; }

    for (int k0 = 0; k0 < KPS; k0 += TK) {
        float dot[4][4];
        #pragma unroll
        for (int i = 0; i < 4; i++)
            #pragma unroll
            for (int j = 0; j < 4; j++) dot[i][j] = 0.f;

        for (int d0 = 0; d0 < DM; d0 += 64) {
            __syncthreads();
            const int d04 = d0 >> 2;
            #pragma unroll
            for (int r = 0; r < 4; r++) {
                int row = srow + 16 * r;
                float4 xv = x4[(size_t)(t0 + row) * 64 + d04 + sc4];
                *(float4*)&xs[row * LDSW + sc4 * 4] = xv;
                int gc = sc4 ^ ((row >> 2) & 7);
                float4 cv = cb4[(size_t)(kb0 + k0 + row) * 64 + d04 + gc];
                *(float4*)&cs[row * LDSW + sc4 * 4] = cv;
            }
            __syncthreads();

            #pragma unroll
            for (int u = 0; u < 16; u++) {
                float4 xa[4];
                #pragma unroll
                for (int i = 0; i < 4; i++)
                    xa[i] = *(const float4*)&xs[(ty * 4 + i) * LDSW + u * 4];
                const int ww = u ^ txc;
                float4 cv[4];
                #pragma unroll
                for (int j = 0; j < 4; j++)
                    cv[j] = *(const float4*)&cs[(tx * 4 + j) * LDSW + ww * 4];
                #pragma unroll
                for (int i = 0; i < 4; i++)
                    #pragma unroll
                    for (int j = 0; j < 4; j++) {
                        dot[i][j] = fmaf(xa[i].x, cv[j].x, dot[i][j]);
                        dot[i][j] = fmaf(xa[i].y, cv[j].y, dot[i][j]);
                        dot[i][j] = fmaf(xa[i].z, cv[j].z, dot[i][j]);
                        dot[i][j] = fmaf(xa[i].w, cv[j].w, dot[i][j]);
                    }
            }
        }

        const int kk0 = kb0 + k0 + tx * 4;
        #pragma unroll
        for (int i = 0; i < 4; i++)
            #pragma unroll
            for (int j = 0; j < 4; j++) {
                float d = dot[i][j];
                int   kk = kk0 + j;
                if (d > mv[i][3]) {
                    if (d > mv[i][1]) {
                        if (d > mv[i][0]) {
                            mv[i][3]=mv[i][2]; mi[i][3]=mi[i][2];
                            mv[i][2]=mv[i][1]; mi[i][2]=mi[i][1];
                            mv[i][1]=mv[i][0]; mi[i][1]=mi[i][0];
                            mv[i][0]=d;        mi[i][0]=kk;
                        } else {
                            mv[i][3]=mv[i][2]; mi[i][3]=mi[i][2];
                            mv[i][2]=mv[i][1]; mi[i][2]=mi[i][1];
                            mv[i][1]=d;        mi[i][1]=kk;
                        }
                    } else {
                        if (d > mv[i][2]) {
                            mv[i][3]=mv[i][2]; mi[i][3]=mi[i][2];
                            mv[i][2]=d;        mi[i][2]=kk;
                        } else {
                            mv[i][3]=d;        mi[i][3]=kk;
                        }
                    }
                }
            }
    }

    #pragma unroll
    for (int i = 0; i < 4; i++) {
        int t = t0 + ty * 4 + i;
        float4 v4 = { mv[i][0], mv[i][1], mv[i][2], mv[i][3] };
        float4 k4 = { (float)mi[i][0], (float)mi[i][1], (float)mi[i][2], (float)mi[i][3] };
        float4* dst = (float4*)(out + (size_t)t * DM + (split * 16 + tx) * 8);
        dst[0] = v4;
        dst[1] = k4;
    }
}

__global__ __launch_bounds__(256) void k_gather_f32(const float* __restrict__ x,
                                                    const float* __restrict__ cb,
                                                    float* __restrict__ out,
                                                    float* __restrict__ lp) {
    __shared__ float4 xls[4][64];
    __shared__ int candk[4][20];
    __shared__ float bsum[4];

    const int w = threadIdx.x >> 6;
    const int L = threadIdx.x & 63;
    const int t = blockIdx.x * 4 + w;

    const float4 xv = ((const float4*)x)[(size_t)t * 64 + L];
    xls[w][L] = xv;
    const float4 f = ((const float4*)(out + (size_t)t * DM))[L];
    const bool even = ((L & 1) == 0);

    double dl = (double)xv.x * xv.x + (double)xv.y * xv.y
              + (double)xv.z * xv.z + (double)xv.w * xv.w;
    #pragma unroll
    for (int off = 32; off; off >>= 1) dl += __shfl_xor(dl, off);
    const float x2 = (float)dl;

    float lm = even ? fmaxf(fmaxf(f.x, f.y), fmaxf(f.z, f.w)) : -FLT_MAX;
    #pragma unroll
    for (int off = 32; off; off >>= 1) lm = fmaxf(lm, __shfl_xor(lm, off));
    const float thr = lm - 5e-5f;

    int ncand = 0;
    #pragma unroll
    for (int j = 0; j < 4; j++) {
        float vj = (j == 0) ? f.x : (j == 1) ? f.y : (j == 2) ? f.z : f.w;
        bool flag = even && (vj >= thr);
        unsigned long long bal = __ballot(flag);
        while (bal) {
            int src = __ffsll(bal) - 1;
            bal &= bal - 1;
            float kv = __shfl(vj, src + 1);
            if (L == 0 && ncand < 20) candk[w][ncand] = (int)kv;
            ncand++;
        }
    }
    if (ncand > 16) ncand = 16;

    int best;
    if (ncand == 1) {
        best = candk[w][0];
    } else {
        const int g = L >> 2, l4 = L & 3;
        float sex = FLT_MAX;
        int   kk  = 0x7fffffff;
        if (g < ncand) {
            kk = candk[w][g];
            const float* xr = (const float*)&xls[w][0];
            const float* cr = cb + (size_t)kk * DM;
            float acc = 0.f;
            {
#pragma clang fp contract(off)
                #pragma unroll 8
                for (int m = 0; m < 64; m++) {
                    float p = xr[4 * m + l4] * cr[4 * m + l4];
                    acc = acc + p;
                }
            }
            float t1 = acc + __shfl_xor(acc, 1);
            float xc = t1 + __shfl_xor(t1, 2);
            sex = x2 - 2.0f * xc;
        }
        #pragma unroll
        for (int off = 32; off; off >>= 1) {
            float os = __shfl_xor(sex, off);
            int   ok = __shfl_xor(kk, off);
            if (os < sex || (os == sex && ok < kk)) { sex = os; kk = ok; }
        }
        best = kk;
    }

    const float4 cv = ((const float4*)cb)[(size_t)best * 64 + L];
    float4 e, q;
    e.x = cv.x - xv.x; q.x = xv.x + e.x;
    e.y = cv.y - xv.y; q.y = xv.y + e.y;
    e.z = cv.z - xv.z; q.z = xv.z + e.z;
    e.w = cv.w - xv.w; q.w = xv.w + e.w;
    ((float4*)out)[(size_t)t * 64 + L] = q;
    if (L == 0) out[QOFF + t] = (float)best;

    float ls = e.x * e.x + e.y * e.y + e.z * e.z + e.w * e.w;
    #pragma unroll
    for (int off = 32; off; off >>= 1) ls += __shfl_xor(ls, off);
    if (L == 0) bsum[w] = ls;
    __syncthreads();
    if (threadIdx.x == 0)
        lp[blockIdx.x] = bsum[0] + bsum[1] + bsum[2] + bsum[3];
}

// ---------------- shared loss finalize ----------------
__global__ __launch_bounds__(256) void k_loss(const float* __restrict__ lp,
                                              float* __restrict__ out) {
    __shared__ double sd[256];
    double s = 0.0;
    for (int i = threadIdx.x; i < BT / 4; i += 256) s += (double)lp[i];
    sd[threadIdx.x] = s;
    __syncthreads();
    for (int st = 128; st; st >>= 1) {
        if (threadIdx.x < st) sd[threadIdx.x] += sd[threadIdx.x + st];
        __syncthreads();
    }
    if (threadIdx.x == 0)
        out[LOFF] = (float)(2.0 * sd[0] / (double)QOFF);
}

extern "C" void kernel_launch(void* const* d_in, const int* in_sizes, int n_in,
                              void* d_out, int out_size, void* d_ws, size_t ws_size,
                              hipStream_t stream) {
    const float* x  = (const float*)d_in[0];
    const float* cb = (const float*)d_in[1];
    float* out = (float*)d_out;

    if (ws_size >= (size_t)WS_NEED) {
        ushort* wsu = (ushort*)d_ws;
        float*  lp  = (float*)((char*)d_ws + WS_LP_BYTES);
        k_cvt        <<<6144, 256, 0, stream>>>(x, cb, wsu);
        k_main_mfma  <<<512,  256, 0, stream>>>(wsu, out);
        k_gather_mfma<<<BT / 4, 256, 0, stream>>>(x, cb, out, lp);
        k_loss       <<<1,    256, 0, stream>>>(lp, out);
    } else {
        float* lp = (float*)d_ws;
        k_main_f32  <<<(BT / TM) * NSPLIT, 256, 0, stream>>>(x, cb, out);
        k_gather_f32<<<BT / 4,             256, 0, stream>>>(x, cb, out, lp);
        k_loss      <<<1,                  256, 0, stream>>>(lp, out);
    }
}

// Round 5
// 181.983 us; speedup vs baseline: 7.5064x; 1.3024x over previous
//
#include <hip/hip_runtime.h>
#include <float.h>

typedef __attribute__((ext_vector_type(8)))  short short8;
typedef __attribute__((ext_vector_type(16))) float f32x16;

#define BT    16384      // B*T tokens
#define DM    256        // embedding dim
#define KC    8192       // codebook size
#define QOFF  (BT * DM)  // start of indices in d_out
#define LOFF  (QOFF + BT)
#define MARGIN 2e-4f

// ws layout (ushort elems): bf16 x and codebook
#define E_XH 0
#define E_CH (BT * DM)
#define WS_LP_BYTES ((size_t)(BT * DM + KC * DM) * 2)   // 12582912
#define WS_NEED (WS_LP_BYTES + 4096 * 4)

// ======================= MFMA path =======================

__device__ inline ushort bf16rne(float f) {
    unsigned u = __float_as_uint(f);
    return (ushort)((u + 0x7FFFu + ((u >> 16) & 1u)) >> 16);
}

// k_cvt: one-time bf16 round of x and codebook into ws
__global__ __launch_bounds__(256) void k_cvt(const float* __restrict__ x,
                                             const float* __restrict__ cb,
                                             ushort* __restrict__ ws) {
    const int XN = BT * DM / 4;   // 1048576 float4s
    const int CN = KC * DM / 4;   // 524288
    int idx = blockIdx.x * 256 + threadIdx.x;
    const float4* src;
    ushort* dh; int o;
    if (idx < XN) { src = (const float4*)x; dh = ws + E_XH; o = idx; }
    else {
        o = idx - XN;
        if (o >= CN) return;
        src = (const float4*)cb; dh = ws + E_CH;
    }
    float4 v = src[o];
    ushort4 h;
    h.x = bf16rne(v.x);
    h.y = bf16rne(v.y);
    h.z = bf16rne(v.z);
    h.w = bf16rne(v.w);
    ((ushort4*)dh)[o] = h;
}

// k_main_mfma v3: tokens LDS-resident full-D, codes double-buffered,
// 32x32x16 fragments. grid 1024 = 128 token-tiles x 8 splits (bid&7 = XCD).
// Block: 512 thr = 8 waves (wm=w>>1 in 0..3 code 64-groups, wn=w&1 token
// 64-halves); wave tile 64 codes x 64 tokens = 2x2 frags of 32x32.
// LDS 128 KB: tokens 4 panels x [128 rows][64 d], codes 2 bufs x [256][64],
// all with granule^(row&7) swizzle (zero-conflict pattern from R3/R4).
__global__ __launch_bounds__(512, 1) void k_main_mfma(const ushort* __restrict__ ws,
                                                      float* __restrict__ out) {
    __shared__ ushort sTok[4 * 8192];   // 64 KB
    __shared__ ushort sCod[2 * 16384];  // 64 KB

    const int tid = threadIdx.x;
    const int w = tid >> 6, L = tid & 63;
    const int wm = w >> 1, wn = w & 1;
    const int split = blockIdx.x & 7;
    const int t0 = (blockIdx.x >> 3) * 128;
    const int col = L & 31, hi = L >> 5;

    const uint4* ch4 = (const uint4*)(ws + E_CH);
    const uint4* xh4 = (const uint4*)(ws + E_XH);

    const int srowT = tid >> 3;          // staging row-in-64 (0..63)
    const int sgT   = tid & 7;           // staging granule
    const int sswzT = (sgT ^ (srowT & 7)) * 8;   // swizzled elem offset (row&7 invariant mod 64)

    // ---- stage tokens once: 4 panels x 128 rows x 8 granules
    #pragma unroll
    for (int q = 0; q < 8; ++q) {
        int panel = q >> 1;
        int row   = (q & 1) * 64 + srowT;
        uint4 tv = xh4[(size_t)(t0 + row) * 32 + panel * 8 + sgT];
        *(uint4*)(sTok + panel * 8192 + row * 64 + ((sgT ^ (row & 7)) * 8)) = tv;
    }
    // ---- stage code chunk 0 into buf 0 (256 rows x 8 granules)
    #pragma unroll
    for (int q = 0; q < 4; ++q) {
        int row = q * 64 + srowT;
        uint4 tv = ch4[(size_t)(split * 1024 + row) * 32 + sgT];
        *(uint4*)(sCod + row * 64 + sswzT) = tv;
    }
    __syncthreads();

    float v1[2], v2[2]; int k1[2], k2[2];
    #pragma unroll
    for (int j = 0; j < 2; ++j) { v1[j] = -FLT_MAX; v2[j] = -FLT_MAX; k1[j] = 0; k2[j] = 0; }

    int buf = 0;
    for (int ct = 0; ct < 4; ++ct) {
        const int cb0 = split * 1024 + ct * 256;

        f32x16 acc[2][2];
        #pragma unroll
        for (int i = 0; i < 2; ++i)
            #pragma unroll
            for (int j = 0; j < 2; ++j)
                #pragma unroll
                for (int e = 0; e < 16; ++e) acc[i][j][e] = 0.f;

        for (int dc = 0; dc < 4; ++dc) {
            const int cidx = ct * 4 + dc;

            // prefetch next code chunk (global -> regs), issued before compute
            uint4 pf[4];
            if (cidx < 15) {
                const int ncb0 = split * 1024 + ((cidx + 1) >> 2) * 256;
                const int ndg  = ((cidx + 1) & 3) * 8;
                #pragma unroll
                for (int q = 0; q < 4; ++q) {
                    int row = q * 64 + srowT;
                    pf[q] = ch4[(size_t)(ncb0 + row) * 32 + ndg + sgT];
                }
            }

            // compute current chunk: 4 K=16 steps
            const ushort* cbuf = sCod + buf * 16384;
            const ushort* tpan = sTok + dc * 8192;
            #pragma unroll
            for (int ks = 0; ks < 4; ++ks) {
                const int gq = ks * 2 + hi;
                short8 a[2], b[2];
                #pragma unroll
                for (int i = 0; i < 2; ++i) {
                    int row = wm * 64 + i * 32 + col;
                    a[i] = *(const short8*)(cbuf + row * 64 + ((gq ^ (row & 7)) * 8));
                }
                #pragma unroll
                for (int j = 0; j < 2; ++j) {
                    int row = wn * 64 + j * 32 + col;
                    b[j] = *(const short8*)(tpan + row * 64 + ((gq ^ (row & 7)) * 8));
                }
                #pragma unroll
                for (int i = 0; i < 2; ++i)
                    #pragma unroll
                    for (int j = 0; j < 2; ++j)
                        acc[i][j] = __builtin_amdgcn_mfma_f32_32x32x16_bf16(a[i], b[j], acc[i][j], 0, 0, 0);
            }

            // write prefetched chunk to the other buffer
            if (cidx < 15) {
                ushort* nbuf = sCod + (buf ^ 1) * 16384;
                #pragma unroll
                for (int q = 0; q < 4; ++q)
                    *(uint4*)(nbuf + (q * 64 + srowT) * 64 + sswzT) = pf[q];
            }
            __syncthreads();
            buf ^= 1;
        }

        // top-2 insert per (lane, token frag j), pruned by frag max
        #pragma unroll
        for (int j = 0; j < 2; ++j)
            #pragma unroll
            for (int i = 0; i < 2; ++i) {
                f32x16 A = acc[i][j];
                float m01 = fmaxf(fmaxf(A[0], A[1]), fmaxf(A[2], A[3]));
                float m23 = fmaxf(fmaxf(A[4], A[5]), fmaxf(A[6], A[7]));
                float m45 = fmaxf(fmaxf(A[8], A[9]), fmaxf(A[10], A[11]));
                float m67 = fmaxf(fmaxf(A[12], A[13]), fmaxf(A[14], A[15]));
                float m = fmaxf(fmaxf(m01, m23), fmaxf(m45, m67));
                if (m > v2[j]) {
                    const int cbase = cb0 + wm * 64 + i * 32 + 4 * hi;
                    #pragma unroll
                    for (int r = 0; r < 16; ++r) {
                        float d = A[r];
                        int kk = cbase + (r & 3) + 8 * (r >> 2);
                        if (d > v2[j]) {
                            if (d > v1[j]) { v2[j] = v1[j]; k2[j] = k1[j]; v1[j] = d; k1[j] = kk; }
                            else           { v2[j] = d; k2[j] = kk; }
                        }
                    }
                }
            }
    }

    // epilogue: 64 candidate slots per token, slot = split*8 + wm*2 + hi
    const int slot = split * 8 + wm * 2 + hi;
    #pragma unroll
    for (int j = 0; j < 2; ++j) {
        int token = t0 + wn * 64 + j * 32 + col;
        float4 o = { v1[j], (float)k1[j], v2[j], (float)k2[j] };
        *(float4*)(out + (size_t)token * DM + slot * 4) = o;
    }
}

// k_gather_mfma: candidates from 64 slots, exact np-f32 re-check, gather, loss
__global__ __launch_bounds__(256) void k_gather_mfma(const float* __restrict__ x,
                                                     const float* __restrict__ cb,
                                                     float* __restrict__ out,
                                                     float* __restrict__ lp) {
    __shared__ float4 xls[4][64];
    __shared__ int candk[4][16];
    __shared__ float bsum[4];

    const int w = threadIdx.x >> 6;
    const int L = threadIdx.x & 63;
    const int t = blockIdx.x * 4 + w;

    const float4 xv = ((const float4*)x)[(size_t)t * 64 + L];
    xls[w][L] = xv;
    const float4 f = ((const float4*)(out + (size_t)t * DM))[L];   // slot L
    __syncthreads();   // drain slot reads before row overwrite

    // x2 (any f32 within ~1e-4 of numpy's: uniform grid shift)
    double dl = (double)xv.x * xv.x + (double)xv.y * xv.y
              + (double)xv.z * xv.z + (double)xv.w * xv.w;
    #pragma unroll
    for (int off = 32; off; off >>= 1) dl += __shfl_xor(dl, off);
    const float x2 = (float)dl;

    float lm = fmaxf(f.x, f.z);
    #pragma unroll
    for (int off = 32; off; off >>= 1) lm = fmaxf(lm, __shfl_xor(lm, off));
    const float thr = lm - MARGIN;

    int ncand = 0;
    #pragma unroll
    for (int p = 0; p < 2; ++p) {
        float vv = p ? f.z : f.x;
        float kf = p ? f.w : f.y;
        unsigned long long bal = __ballot(vv >= thr);
        while (bal) {
            int src = __ffsll(bal) - 1;
            bal &= bal - 1;
            float kv = __shfl(kf, src);
            if (L == 0 && ncand < 16) candk[w][ncand] = (int)kv;
            ncand++;
        }
    }
    if (ncand > 16) ncand = 16;

    int best;
    if (ncand == 1) {
        best = candk[w][0];
    } else {
        const int g = L >> 2, l4 = L & 3;
        float sex = FLT_MAX;
        int   kk  = 0x7fffffff;
        if (g < ncand) {
            kk = candk[w][g];
            const float* xr = (const float*)&xls[w][0];
            const float* cr = cb + (size_t)kk * DM;
            float acc = 0.f;
            {
#pragma clang fp contract(off)
                #pragma unroll 8
                for (int m = 0; m < 64; m++) {
                    float p2 = xr[4 * m + l4] * cr[4 * m + l4];
                    acc = acc + p2;
                }
            }
            float t1 = acc + __shfl_xor(acc, 1);   // fl(s0+s1)/fl(s2+s3)
            float xc = t1 + __shfl_xor(t1, 2);     // np 4-acc SSE combine
            sex = x2 - 2.0f * xc;
        }
        #pragma unroll
        for (int off = 32; off; off >>= 1) {
            float os = __shfl_xor(sex, off);
            int   ok = __shfl_xor(kk, off);
            if (os < sex || (os == sex && ok < kk)) { sex = os; kk = ok; }
        }
        best = kk;
    }

    const float4 cv = ((const float4*)cb)[(size_t)best * 64 + L];
    float4 e, q;
    e.x = cv.x - xv.x; q.x = xv.x + e.x;
    e.y = cv.y - xv.y; q.y = xv.y + e.y;
    e.z = cv.z - xv.z; q.z = xv.z + e.z;
    e.w = cv.w - xv.w; q.w = xv.w + e.w;
    ((float4*)out)[(size_t)t * 64 + L] = q;
    if (L == 0) out[QOFF + t] = (float)best;

    float ls = e.x * e.x + e.y * e.y + e.z * e.z + e.w * e.w;
    #pragma unroll
    for (int off = 32; off; off >>= 1) ls += __shfl_xor(ls, off);
    if (L == 0) bsum[w] = ls;
    __syncthreads();
    if (threadIdx.x == 0)
        lp[blockIdx.x] = bsum[0] + bsum[1] + bsum[2] + bsum[3];
}

// ======================= fallback f32 path (round-2, verified) =======================

#define TM    64
#define TK    64
#define NSPLIT 2
#define KPS   (KC / NSPLIT)
#define LDSW  68

__global__ __launch_bounds__(256, 2) void k_main_f32(const float* __restrict__ x,
                                                     const float* __restrict__ cb,
                                                     float* __restrict__ out) {
    __shared__ float xs[TM * LDSW];
    __shared__ float cs[TK * LDSW];

    const int tid = threadIdx.x;
    const int ty = tid >> 4, tx = tid & 15;
    const int split = blockIdx.x & 1;
    const int tb    = blockIdx.x >> 1;
    const int t0    = tb * TM;
    const int kb0   = split * KPS;
    const int txc   = tx & 7;
    const int srow = tid >> 4;
    const int sc4  = tid & 15;
    const float4* x4  = (const float4*)x;
    const float4* cb4 = (const float4*)cb;

    float mv[4][4];
    int   mi[4][4];
    #pragma unroll
    for (int i = 0; i < 4; i++)
        #pragma unroll
        for (int j = 0; j < 4; j++) { mv[i][j] = -FLT_MAX; mi[i][j] = 0; }

    for (int k0 = 0; k0 < KPS; k0 += TK) {
        float dot[4][4];
        #pragma unroll
        for (int i = 0; i < 4; i++)
            #pragma unroll
            for (int j = 0; j < 4; j++) dot[i][j] = 0.f;

        for (int d0 = 0; d0 < DM; d0 += 64) {
            __syncthreads();
            const int d04 = d0 >> 2;
            #pragma unroll
            for (int r = 0; r < 4; r++) {
                int row = srow + 16 * r;
                float4 xv = x4[(size_t)(t0 + row) * 64 + d04 + sc4];
                *(float4*)&xs[row * LDSW + sc4 * 4] = xv;
                int gc = sc4 ^ ((row >> 2) & 7);
                float4 cv = cb4[(size_t)(kb0 + k0 + row) * 64 + d04 + gc];
                *(float4*)&cs[row * LDSW + sc4 * 4] = cv;
            }
            __syncthreads();

            #pragma unroll
            for (int u = 0; u < 16; u++) {
                float4 xa[4];
                #pragma unroll
                for (int i = 0; i < 4; i++)
                    xa[i] = *(const float4*)&xs[(ty * 4 + i) * LDSW + u * 4];
                const int ww = u ^ txc;
                float4 cv[4];
                #pragma unroll
                for (int j = 0; j < 4; j++)
                    cv[j] = *(const float4*)&cs[(tx * 4 + j) * LDSW + ww * 4];
                #pragma unroll
                for (int i = 0; i < 4; i++)
                    #pragma unroll
                    for (int j = 0; j < 4; j++) {
                        dot[i][j] = fmaf(xa[i].x, cv[j].x, dot[i][j]);
                        dot[i][j] = fmaf(xa[i].y, cv[j].y, dot[i][j]);
                        dot[i][j] = fmaf(xa[i].z, cv[j].z, dot[i][j]);
                        dot[i][j] = fmaf(xa[i].w, cv[j].w, dot[i][j]);
                    }
            }
        }

        const int kk0 = kb0 + k0 + tx * 4;
        #pragma unroll
        for (int i = 0; i < 4; i++)
            #pragma unroll
            for (int j = 0; j < 4; j++) {
                float d = dot[i][j];
                int   kk = kk0 + j;
                if (d > mv[i][3]) {
                    if (d > mv[i][1]) {
                        if (d > mv[i][0]) {
                            mv[i][3]=mv[i][2]; mi[i][3]=mi[i][2];
                            mv[i][2]=mv[i][1]; mi[i][2]=mi[i][1];
                            mv[i][1]=mv[i][0]; mi[i][1]=mi[i][0];
                            mv[i][0]=d;        mi[i][0]=kk;
                        } else {
                            mv[i][3]=mv[i][2]; mi[i][3]=mi[i][2];
                            mv[i][2]=mv[i][1]; mi[i][2]=mi[i][1];
                            mv[i][1]=d;        mi[i][1]=kk;
                        }
                    } else {
                        if (d > mv[i][2]) {
                            mv[i][3]=mv[i][2]; mi[i][3]=mi[i][2];
                            mv[i][2]=d;        mi[i][2]=kk;
                        } else {
                            mv[i][3]=d;        mi[i][3]=kk;
                        }
                    }
                }
            }
    }

    #pragma unroll
    for (int i = 0; i < 4; i++) {
        int t = t0 + ty * 4 + i;
        float4 v4 = { mv[i][0], mv[i][1], mv[i][2], mv[i][3] };
        float4 k4 = { (float)mi[i][0], (float)mi[i][1], (float)mi[i][2], (float)mi[i][3] };
        float4* dst = (float4*)(out + (size_t)t * DM + (split * 16 + tx) * 8);
        dst[0] = v4;
        dst[1] = k4;
    }
}

__global__ __launch_bounds__(256) void k_gather_f32(const float* __restrict__ x,
                                                    const float* __restrict__ cb,
                                                    float* __restrict__ out,
                                                    float* __restrict__ lp) {
    __shared__ float4 xls[4][64];
    __shared__ int candk[4][20];
    __shared__ float bsum[4];

    const int w = threadIdx.x >> 6;
    const int L = threadIdx.x & 63;
    const int t = blockIdx.x * 4 + w;

    const float4 xv = ((const float4*)x)[(size_t)t * 64 + L];
    xls[w][L] = xv;
    const float4 f = ((const float4*)(out + (size_t)t * DM))[L];
    const bool even = ((L & 1) == 0);

    double dl = (double)xv.x * xv.x + (double)xv.y * xv.y
              + (double)xv.z * xv.z + (double)xv.w * xv.w;
    #pragma unroll
    for (int off = 32; off; off >>= 1) dl += __shfl_xor(dl, off);
    const float x2 = (float)dl;

    float lm = even ? fmaxf(fmaxf(f.x, f.y), fmaxf(f.z, f.w)) : -FLT_MAX;
    #pragma unroll
    for (int off = 32; off; off >>= 1) lm = fmaxf(lm, __shfl_xor(lm, off));
    const float thr = lm - 5e-5f;

    int ncand = 0;
    #pragma unroll
    for (int j = 0; j < 4; j++) {
        float vj = (j == 0) ? f.x : (j == 1) ? f.y : (j == 2) ? f.z : f.w;
        bool flag = even && (vj >= thr);
        unsigned long long bal = __ballot(flag);
        while (bal) {
            int src = __ffsll(bal) - 1;
            bal &= bal - 1;
            float kv = __shfl(vj, src + 1);
            if (L == 0 && ncand < 20) candk[w][ncand] = (int)kv;
            ncand++;
        }
    }
    if (ncand > 16) ncand = 16;

    int best;
    if (ncand == 1) {
        best = candk[w][0];
    } else {
        const int g = L >> 2, l4 = L & 3;
        float sex = FLT_MAX;
        int   kk  = 0x7fffffff;
        if (g < ncand) {
            kk = candk[w][g];
            const float* xr = (const float*)&xls[w][0];
            const float* cr = cb + (size_t)kk * DM;
            float acc = 0.f;
            {
#pragma clang fp contract(off)
                #pragma unroll 8
                for (int m = 0; m < 64; m++) {
                    float p = xr[4 * m + l4] * cr[4 * m + l4];
                    acc = acc + p;
                }
            }
            float t1 = acc + __shfl_xor(acc, 1);
            float xc = t1 + __shfl_xor(t1, 2);
            sex = x2 - 2.0f * xc;
        }
        #pragma unroll
        for (int off = 32; off; off >>= 1) {
            float os = __shfl_xor(sex, off);
            int   ok = __shfl_xor(kk, off);
            if (os < sex || (os == sex && ok < kk)) { sex = os; kk = ok; }
        }
        best = kk;
    }

    const float4 cv = ((const float4*)cb)[(size_t)best * 64 + L];
    float4 e, q;
    e.x = cv.x - xv.x; q.x = xv.x + e.x;
    e.y = cv.y - xv.y; q.y = xv.y + e.y;
    e.z = cv.z - xv.z; q.z = xv.z + e.z;
    e.w = cv.w - xv.w; q.w = xv.w + e.w;
    ((float4*)out)[(size_t)t * 64 + L] = q;
    if (L == 0) out[QOFF + t] = (float)best;

    float ls = e.x * e.x + e.y * e.y + e.z * e.z + e.w * e.w;
    #pragma unroll
    for (int off = 32; off; off >>= 1) ls += __shfl_xor(ls, off);
    if (L == 0) bsum[w] = ls;
    __syncthreads();
    if (threadIdx.x == 0)
        lp[blockIdx.x] = bsum[0] + bsum[1] + bsum[2] + bsum[3];
}

// ---------------- shared loss finalize ----------------
__global__ __launch_bounds__(256) void k_loss(const float* __restrict__ lp,
                                              float* __restrict__ out) {
    __shared__ double sd[256];
    double s = 0.0;
    for (int i = threadIdx.x; i < BT / 4; i += 256) s += (double)lp[i];
    sd[threadIdx.x] = s;
    __syncthreads();
    for (int st = 128; st; st >>= 1) {
        if (threadIdx.x < st) sd[threadIdx.x] += sd[threadIdx.x + st];
        __syncthreads();
    }
    if (threadIdx.x == 0)
        out[LOFF] = (float)(2.0 * sd[0] / (double)QOFF);
}

extern "C" void kernel_launch(void* const* d_in, const int* in_sizes, int n_in,
                              void* d_out, int out_size, void* d_ws, size_t ws_size,
                              hipStream_t stream) {
    const float* x  = (const float*)d_in[0];
    const float* cb = (const float*)d_in[1];
    float* out = (float*)d_out;

    if (ws_size >= (size_t)WS_NEED) {
        ushort* wsu = (ushort*)d_ws;
        float*  lp  = (float*)((char*)d_ws + WS_LP_BYTES);
        k_cvt        <<<6144, 256, 0, stream>>>(x, cb, wsu);
        k_main_mfma  <<<1024, 512, 0, stream>>>(wsu, out);
        k_gather_mfma<<<BT / 4, 256, 0, stream>>>(x, cb, out, lp);
        k_loss       <<<1,    256, 0, stream>>>(lp, out);
    } else {
        float* lp = (float*)d_ws;
        k_main_f32  <<<(BT / TM) * NSPLIT, 256, 0, stream>>>(x, cb, out);
        k_gather_f32<<<BT / 4,             256, 0, stream>>>(x, cb, out, lp);
        k_loss      <<<1,                  256, 0, stream>>>(lp, out);
    }
}